// Round 2
// 2234.403 us; speedup vs baseline: 1.1212x; 1.1212x over previous
//
#include <hip/hip_runtime.h>
#include <math.h>

#define N_IN   65536
#define N_UP   262144
#define N_OUT  131072
#define C_IN   128
#define C_OUT  64
#define K1     27
#define K2     27
#define K3     16
#define M1     65536
#define M2     131072
#define M3     131072
#define EPSV   1e-6f
#define WPK    256          // waves per kernel-offset
#define WPK_SHIFT 8

// Outer-product sparse conv: lane = gathered row. Each wave owns offset k and
// R = M/WPK rows, processed in batches of 64 (one row per lane).
//  - x rows: per-lane float4 gathers, chunk-rotated (xa in use, xb arriving)
//  - cross-batch pipeline: next row's indices + chunks 0,1 issue BEFORE the
//    scatter atomics, so the next FMA block's s_waitcnt resolves without
//    draining the atomic burst (vmcnt retires oldest-first; the prefetch
//    loads are older than the atomics)
//  - weights: wave-uniform -> scalar loads broadcast into FMA s-operand
//  - acc[64] fp32 per lane; scatter via LDS transpose -> row-contiguous
//    scalar atomics (global_atomic_add_f32 fire-and-forget)
template <int CIN, int MSHIFT>
__global__ __launch_bounds__(256) void conv_gemm(
    const float* __restrict__ X, const float* __restrict__ W,
    const int* __restrict__ kin, const int* __restrict__ kout,
    float* __restrict__ outp)
{
    __shared__ float lds_t[4][64][20];   // [wave][row][16 ch + pad], float4-aligned
    __shared__ int   lds_dst[4][64];

    const int lane = threadIdx.x & 63;
    const int wv   = threadIdx.x >> 6;
    const int wave = blockIdx.x * 4 + wv;
    const int k    = __builtin_amdgcn_readfirstlane(wave >> WPK_SHIFT);
    const int widx = wave & (WPK - 1);
    constexpr int R  = (1 << MSHIFT) / WPK;
    constexpr int NB = R / 64;
    constexpr int KC = CIN / 16;

    const float* Wk = W + (size_t)k * (CIN * 64);
    const int base = (k << MSHIFT) + widx * R;

    // prologue: row-0 indices + chunks 0,1 (KC >= 2 always: CIN >= 32)
    int src = kin[base + lane];
    int dst = kout[base + lane];
    const float4* xr0 = (const float4*)(X + (size_t)src * CIN);
    float4 xa0 = xr0[0], xa1 = xr0[1], xa2 = xr0[2], xa3 = xr0[3];
    float4 xb0 = xr0[4], xb1 = xr0[5], xb2 = xr0[6], xb3 = xr0[7];

    for (int b = 0; b < NB; ++b) {
        lds_dst[wv][lane] = dst;

        // next-batch indices: issue first (longest dependency chain:
        // idx -> addr -> gather). Hidden under this batch's FMA.
        int srcn, dstn;
        if (b + 1 < NB) {
            const int jn = base + (b + 1) * 64 + lane;
            srcn = kin[jn];
            dstn = kout[jn];
        } else {
            srcn = src; dstn = dst;   // harmless re-read on final batch
        }

        float acc[64];
#pragma unroll
        for (int c = 0; c < 64; ++c) acc[c] = 0.f;

        const float4* xr = (const float4*)(X + (size_t)src * CIN);

        for (int kc = 0; kc < KC; ++kc) {
            // while FMAing chunk kc: fetch chunk kc+2 of this row, or — on the
            // last two iterations — chunks 0,1 of the NEXT row (so they sit in
            // the vmcnt queue ahead of this batch's atomics).
            float4 xc0, xc1, xc2, xc3;
            if (kc + 2 < KC) {
                xc0 = xr[(kc + 2) * 4 + 0];
                xc1 = xr[(kc + 2) * 4 + 1];
                xc2 = xr[(kc + 2) * 4 + 2];
                xc3 = xr[(kc + 2) * 4 + 3];
            } else {
                const int m = kc + 2 - KC;   // 0 or 1: next row chunk index
                const float4* xrn = (const float4*)(X + (size_t)srcn * CIN);
                xc0 = xrn[m * 4 + 0];
                xc1 = xrn[m * 4 + 1];
                xc2 = xrn[m * 4 + 2];
                xc3 = xrn[m * 4 + 3];
            }

            float xs[16];
            xs[0]=xa0.x; xs[1]=xa0.y; xs[2]=xa0.z; xs[3]=xa0.w;
            xs[4]=xa1.x; xs[5]=xa1.y; xs[6]=xa1.z; xs[7]=xa1.w;
            xs[8]=xa2.x; xs[9]=xa2.y; xs[10]=xa2.z; xs[11]=xa2.w;
            xs[12]=xa3.x; xs[13]=xa3.y; xs[14]=xa3.z; xs[15]=xa3.w;

            const float* wrow = Wk + kc * 16 * 64;
#pragma unroll
            for (int i = 0; i < 16; ++i) {
                const float xi = xs[i];
                const float* wr = wrow + i * 64;   // wave-uniform -> s_load
#pragma unroll
                for (int c = 0; c < 64; ++c)
                    acc[c] = fmaf(xi, wr[c], acc[c]);
            }
            xa0 = xb0; xa1 = xb1; xa2 = xb2; xa3 = xb3;
            xb0 = xc0; xb1 = xc1; xb2 = xc2; xb3 = xc3;
        }
        // here xa/xb already hold NEXT row chunks 0,1 — loads in flight,
        // queued BEFORE the atomics below.

        // scatter: transpose 16 channels at a time through LDS, then
        // row-contiguous scalar atomics. Same-wave LDS ops are in-order;
        // slices private -> no barrier needed.
        const int c16 = lane & 15;
#pragma unroll
        for (int cc = 0; cc < 4; ++cc) {
#pragma unroll
            for (int q = 0; q < 4; ++q) {
                float4 v;
                v.x = acc[cc * 16 + q * 4 + 0];
                v.y = acc[cc * 16 + q * 4 + 1];
                v.z = acc[cc * 16 + q * 4 + 2];
                v.w = acc[cc * 16 + q * 4 + 3];
                *(float4*)&lds_t[wv][lane][q * 4] = v;
            }
            // batch LDS reads into regs first (one lgkm wait), then burst
            // the 16 atomics back-to-back.
            float sv[16];
            int   sd[16];
#pragma unroll
            for (int t = 0; t < 16; ++t) {
                const int rr = (lane >> 4) + 4 * t;
                sv[t] = lds_t[wv][rr][c16];
                sd[t] = lds_dst[wv][rr];
            }
#pragma unroll
            for (int t = 0; t < 16; ++t)
                atomicAdd(outp + (size_t)sd[t] * 64 + cc * 16 + c16, sv[t]);
        }

        src = srcn;
        dst = dstn;
    }
}

// Per-channel sum/sumsq; LDS reduce across the block's 4 waves, then atomics.
__global__ __launch_bounds__(256) void stats_kernel(
    const float* __restrict__ x, int nrows, float* __restrict__ stats)
{
    __shared__ float sh[2][4][64];
    const int c  = threadIdx.x & 63;
    const int rw = threadIdx.x >> 6;
    float s = 0.f, s2 = 0.f;
    for (int r = blockIdx.x * 4 + rw; r < nrows; r += gridDim.x * 4) {
        float v = x[(size_t)r * 64 + c];
        s += v;
        s2 = fmaf(v, v, s2);
    }
    sh[0][rw][c] = s;
    sh[1][rw][c] = s2;
    __syncthreads();
    if (rw == 0) {
        s  = (sh[0][0][c] + sh[0][1][c]) + (sh[0][2][c] + sh[0][3][c]);
        s2 = (sh[1][0][c] + sh[1][1][c]) + (sh[1][2][c] + sh[1][3][c]);
        atomicAdd(stats + c, s);
        atomicAdd(stats + 64 + c, s2);
    }
}

// stats[128+c]=mean, stats[192+c]=rsqrt(var+eps)
__global__ void finalize_stats(float* stats, float inv_n)
{
    const int c = threadIdx.x;   // 64 threads
    float mu  = stats[c] * inv_n;
    float var = stats[64 + c] * inv_n - mu * mu;
    stats[128 + c] = mu;
    stats[192 + c] = rsqrtf(var + EPSV);
}

// x = elu((x-mu)*scale) (+ fp32 encoder skip if enc != null), in place.
__global__ __launch_bounds__(256) void norm_elu(
    float* __restrict__ x, const float* __restrict__ stats,
    const float* __restrict__ enc)
{
    const int i = blockIdx.x * 256 + threadIdx.x;
    const int c = i & 63;
    float v = (x[i] - stats[128 + c]) * stats[192 + c];
    v = (v > 0.f) ? v : expm1f(v);
    if (enc) v += enc[i];
    x[i] = v;
}

// Final: normalize+elu, pruning dot, keep mask, fp32 outputs.
__global__ __launch_bounds__(256) void final_kernel(
    const float* __restrict__ x, const float* __restrict__ stats,
    const float* __restrict__ Wp, const float* __restrict__ bp,
    float* __restrict__ outp)
{
    const int lane = threadIdx.x & 63;
    const int wid  = threadIdx.x >> 6;
    const int row  = blockIdx.x * 4 + wid;

    float v = (x[(size_t)row * 64 + lane] - stats[128 + lane]) * stats[192 + lane];
    v = (v > 0.f) ? v : expm1f(v);

    float p = v * Wp[lane];
#pragma unroll
    for (int m = 1; m < 64; m <<= 1)
        p += __shfl_xor(p, m, 64);
    p += bp[0];

    const bool keep = p > 0.0f;
    outp[(size_t)row * 64 + lane] = keep ? v : 0.f;
    if (lane == 0)
        outp[(size_t)N_OUT * 64 + row] = keep ? 1.f : 0.f;
}

extern "C" void kernel_launch(void* const* d_in, const int* in_sizes, int n_in,
                              void* d_out, int out_size, void* d_ws, size_t ws_size,
                              hipStream_t stream)
{
    const float* in_feats = (const float*)d_in[0];   // [65536,128] f32
    const float* enc      = (const float*)d_in[1];   // [262144,64] f32
    const float* W1       = (const float*)d_in[2];   // [27,128,64] f32
    const float* W2       = (const float*)d_in[3];   // [27,64,64]  f32
    const float* W3       = (const float*)d_in[4];   // [16,64,64]  f32
    const float* Wp       = (const float*)d_in[5];   // [64,1] f32
    const float* bp       = (const float*)d_in[6];   // [1] f32
    const int* kin1  = (const int*)d_in[7];
    const int* kout1 = (const int*)d_in[8];
    const int* kin2  = (const int*)d_in[9];
    const int* kout2 = (const int*)d_in[10];
    const int* kin3  = (const int*)d_in[11];
    const int* kout3 = (const int*)d_in[12];
    float* outp = (float*)d_out;

    char* ws = (char*)d_ws;
    float* up_a   = (float*)ws;                         // 64 MB  [262144,64] f32
    float* up_b   = (float*)(ws + 67108864);            // 64 MB  [262144,64] f32
    float* out3   = up_a;                               // 32 MB reuse after conv2
    float* statsA = (float*)(ws + 134217728);           // 256 f32 each
    float* statsB = statsA + 256;
    float* statsC = statsA + 512;

    (void)hipMemsetAsync(up_a, 0, (size_t)N_UP * 64 * 4, stream);
    (void)hipMemsetAsync(up_b, 0, (size_t)N_UP * 64 * 4, stream);
    (void)hipMemsetAsync(statsA, 0, 3 * 256 * 4, stream);

    // ---- dec_block_1a: conv-transpose (gather input_feats, scatter to up_a)
    conv_gemm<128, 16><<<(K1 * WPK) / 4, 256, 0, stream>>>(
        in_feats, W1, kin1, kout1, up_a);
    stats_kernel<<<512, 256, 0, stream>>>(up_a, N_UP, statsA);
    finalize_stats<<<1, 64, 0, stream>>>(statsA, 1.f / N_UP);
    norm_elu<<<(N_UP * 64) / 256, 256, 0, stream>>>(up_a, statsA, nullptr);

    // ---- dec_block_1b: conv 3x3x3 (up_a -> up_b)
    conv_gemm<64, 17><<<(K2 * WPK) / 4, 256, 0, stream>>>(
        up_a, W2, kin2, kout2, up_b);
    stats_kernel<<<512, 256, 0, stream>>>(up_b, N_UP, statsB);
    finalize_stats<<<1, 64, 0, stream>>>(statsB, 1.f / N_UP);
    norm_elu<<<(N_UP * 64) / 256, 256, 0, stream>>>(up_b, statsB, enc);  // + skip

    // ---- dec_block_2: conv k=2 (up_b -> out3), out3 reuses up_a storage
    (void)hipMemsetAsync(out3, 0, (size_t)N_OUT * 64 * 4, stream);
    conv_gemm<64, 17><<<(K3 * WPK) / 4, 256, 0, stream>>>(
        up_b, W3, kin3, kout3, out3);
    stats_kernel<<<512, 256, 0, stream>>>(out3, N_OUT, statsC);
    finalize_stats<<<1, 64, 0, stream>>>(statsC, 1.f / N_OUT);

    // ---- pruning head + fp32 outputs
    final_kernel<<<N_OUT / 4, 256, 0, stream>>>(out3, statsC, Wp, bp, outp);
}